// Round 6
// baseline (43.124 us; speedup 1.0000x reference)
//
#include <hip/hip_runtime.h>
#include <math.h>

typedef _Float16 f16x8 __attribute__((ext_vector_type(8)));
typedef __fp16   fp16v2 __attribute__((ext_vector_type(2)));
typedef float    f32x16 __attribute__((ext_vector_type(16)));

#define THREADS 256
#define YHALF   4096  // y points per block (half of N), 32 KB LDS
#define XPB     128   // x points per block (4 waves * 32 cols)

static __device__ inline unsigned pk2(float a, float b) {
    fp16v2 h = __builtin_amdgcn_cvt_pkrtz(a, b);
    return __builtin_bit_cast(unsigned, h);
}

// Init per-point min array to 0x7F7F7F7F (float ~3.39e38, > any distance).
__global__ void init_min_ws(int4* __restrict__ ws, int n4) {
    int i = blockIdx.x * blockDim.x + threadIdx.x;
    if (i < n4) ws[i] = make_int4(0x7F7F7F7F, 0x7F7F7F7F, 0x7F7F7F7F, 0x7F7F7F7F);
}

// One wave owns 32 x-points (MFMA cols); block scans HALF of y (4096 rows).
// A[y,k] = (y0,y1,y2,|y|^2) f16; B[k,x] = (-2x0,-2x1,-2x2,1) f16, K slots
// 4..15 zero IN B so garbage in A's unused K slots contributes 0.
// acc = d^2 - |x|^2; running min on VALU (v_min3); the two y-half blocks
// merge via int-punned atomicMin (monotonic for our value range).
__global__ __launch_bounds__(THREADS, 4) void chamfer_kernel(
    const float* __restrict__ pred, const float* __restrict__ targ,
    int* __restrict__ minArr, int N)
{
    const int dir  = blockIdx.z;
    const int b    = blockIdx.y >> 1;
    const int half = blockIdx.y & 1;
    const float* xsrc = dir == 0 ? pred : targ;
    const float* ysrc = dir == 0 ? targ : pred;

    __shared__ uint2 sy[YHALF];   // (y0,y1) (y2,|y|^2) packed f16

    const int tid  = threadIdx.x;
    const int lane = tid & 63;
    const int wave = tid >> 6;
    const int col  = lane & 31;

    // This lane's x column (lanes 32-63 duplicate lanes 0-31).
    const int    xIdx = blockIdx.x * XPB + wave * 32 + col;
    const size_t xi   = (size_t)(b * N + xIdx) * 3;
    const float x0 = xsrc[xi], x1 = xsrc[xi + 1], x2 = xsrc[xi + 2];

    const bool act = lane < 32;
    f16x8 bf;
    bf[0] = act ? (_Float16)(-2.0f * x0) : (_Float16)0.0f;
    bf[1] = act ? (_Float16)(-2.0f * x1) : (_Float16)0.0f;
    bf[2] = act ? (_Float16)(-2.0f * x2) : (_Float16)0.0f;
    bf[3] = act ? (_Float16)1.0f : (_Float16)0.0f;
    bf[4] = bf[5] = bf[6] = bf[7] = (_Float16)0.0f;

    f32x16 zacc;
    f32x16 vmin;
#pragma unroll
    for (int r = 0; r < 16; ++r) { zacc[r] = 0.0f; vmin[r] = INFINITY; }

    // Stage this block's y-half (16 points per thread), coalesced loads.
    const float* ybase = ysrc + (size_t)b * N * 3 + (size_t)half * YHALF * 3;
#pragma unroll
    for (int j = 0; j < YHALF / THREADS; ++j) {
        const int    yj = j * THREADS + tid;
        const float* yp = ybase + (size_t)yj * 3;
        float y0 = yp[0], y1 = yp[1], y2v = yp[2];
        float nn = fmaf(y0, y0, fmaf(y1, y1, y2v * y2v));
        sy[yj] = make_uint2(pk2(y0, y1), pk2(y2v, nn));
    }
    __syncthreads();

    // Barrier-free main loop: ds_read_b64 -> MFMA -> v_min3 stream.
#pragma unroll 2
    for (int i = 0; i < YHALF / 32; i += 2) {
        uint2 lo0 = sy[i * 32 + col];
        uint2 lo1 = sy[(i + 1) * 32 + col];
        uint4 av0 = make_uint4(lo0.x, lo0.y, 0u, 0u);
        uint4 av1 = make_uint4(lo1.x, lo1.y, 0u, 0u);
        f32x16 acc0 = __builtin_amdgcn_mfma_f32_32x32x16_f16(
            __builtin_bit_cast(f16x8, av0), bf, zacc, 0, 0, 0);
        f32x16 acc1 = __builtin_amdgcn_mfma_f32_32x32x16_f16(
            __builtin_bit_cast(f16x8, av1), bf, zacc, 0, 0, 0);
#pragma unroll
        for (int r = 0; r < 16; ++r)
            vmin[r] = fminf(fminf(vmin[r], acc0[r]), acc1[r]);  // v_min3
    }

    // Fold 16 regs, then the two row-halves (lane ^ 32) -> full min per col.
    float v = vmin[0];
#pragma unroll
    for (int r = 1; r < 16; ++r) v = fminf(v, vmin[r]);
    v = fminf(v, __shfl_xor(v, 32));
    float d = v + fmaf(x0, x0, fmaf(x1, x1, x2 * x2));  // + |x|^2 in f32

    if (act)
        atomicMin(&minArr[(dir * 4 + b) * N + xIdx], __float_as_int(d));
}

// dist = (sum of all mins)/ (B*N) summed over dirs; out = (loss, dist, rate).
__global__ __launch_bounds__(1024) void finalize(
    const int* __restrict__ minArr, const float* __restrict__ fbpp,
    float* __restrict__ out, int totalPts)
{
    __shared__ float sw[16];
    const int tid = threadIdx.x;
    float s = 0.0f;
    for (int i = tid; i < 2 * totalPts; i += 1024)
        s += __int_as_float(minArr[i]);
#pragma unroll
    for (int off = 32; off > 0; off >>= 1) s += __shfl_xor(s, off);
    if ((tid & 63) == 0) sw[tid >> 6] = s;
    __syncthreads();
    if (tid == 0) {
        float t = 0.0f;
#pragma unroll
        for (int w = 0; w < 16; ++w) t += sw[w];
        float dist = t / (float)totalPts;
        float rate = fbpp[0];
        out[0] = dist + rate;
        out[1] = dist;
        out[2] = rate;
    }
}

extern "C" void kernel_launch(void* const* d_in, const int* in_sizes, int n_in,
                              void* d_out, int out_size, void* d_ws, size_t ws_size,
                              hipStream_t stream) {
    const float* pred = (const float*)d_in[0];
    const float* targ = (const float*)d_in[1];
    const float* fbpp = (const float*)d_in[2];
    float* out = (float*)d_out;

    const int B = 4;
    const int N = in_sizes[0] / (B * 3);   // 8192
    int* minArr = (int*)d_ws;              // 2 * B * N ints = 256 KB

    const int n4 = (2 * B * N) / 4;        // int4 count = 16384
    init_min_ws<<<(n4 + 255) / 256, 256, 0, stream>>>((int4*)d_ws, n4);

    dim3 grid(N / XPB, B * 2, 2);          // (64, 8, 2) = 1024 blocks
    chamfer_kernel<<<grid, THREADS, 0, stream>>>(pred, targ, minArr, N);

    finalize<<<1, 1024, 0, stream>>>(minArr, fbpp, out, B * N);
}

// Round 7
// 24.886 us; speedup vs baseline: 1.7329x; 1.7329x over previous
//
#include <hip/hip_runtime.h>
#include <math.h>

typedef _Float16 f16x8 __attribute__((ext_vector_type(8)));
typedef __fp16   fp16v2 __attribute__((ext_vector_type(2)));
typedef float    f32x16 __attribute__((ext_vector_type(16)));

#define THREADS 256
#define YCHUNK  4096  // y points per LDS mega-chunk (32 KB)
#define XPB     128   // x points per block (4 waves * 32 cols)

static __device__ inline unsigned pk2(float a, float b) {
    fp16v2 h = __builtin_amdgcn_cvt_pkrtz(a, b);
    return __builtin_bit_cast(unsigned, h);
}

// One wave owns 32 x-points (MFMA cols) and scans ALL y (MFMA rows, 32/instr).
// A[y,k] = (y0,y1,y2,|y|^2) f16; B[k,x] = (-2x0,-2x1,-2x2,1) f16 with all
// other K slots zero IN B, so garbage in A's unused K slots contributes 0.
// acc = d^2 - |x|^2; running min on VALU (v_min3), add |x|^2 (f32) at the end.
// Grid pins occupancy at 2 waves/SIMD -> VGPRs up to 256 are free; keep 8
// MFMA results in flight (named regs, rule #20) to hide MFMA latency.
__global__ __launch_bounds__(THREADS, 2) void chamfer_kernel(
    const float* __restrict__ pred, const float* __restrict__ targ,
    float* __restrict__ partials, int N)
{
    const int dir = blockIdx.z;
    const float* xsrc = dir == 0 ? pred : targ;
    const float* ysrc = dir == 0 ? targ : pred;
    const int b = blockIdx.y;

    __shared__ uint2 sy[YCHUNK];   // (y0,y1) (y2,|y|^2) packed f16
    __shared__ float swave[4];

    const int tid  = threadIdx.x;
    const int lane = tid & 63;
    const int wave = tid >> 6;
    const int col  = lane & 31;

    // This lane's x column (lanes 32-63 duplicate lanes 0-31).
    const size_t xi = (size_t)(b * N + blockIdx.x * XPB + wave * 32 + col) * 3;
    const float x0 = xsrc[xi], x1 = xsrc[xi + 1], x2 = xsrc[xi + 2];

    const bool act = lane < 32;
    f16x8 bf;
    bf[0] = act ? (_Float16)(-2.0f * x0) : (_Float16)0.0f;
    bf[1] = act ? (_Float16)(-2.0f * x1) : (_Float16)0.0f;
    bf[2] = act ? (_Float16)(-2.0f * x2) : (_Float16)0.0f;
    bf[3] = act ? (_Float16)1.0f : (_Float16)0.0f;
    bf[4] = bf[5] = bf[6] = bf[7] = (_Float16)0.0f;

    f32x16 zacc;
    f32x16 vmin;
#pragma unroll
    for (int r = 0; r < 16; ++r) { zacc[r] = 0.0f; vmin[r] = INFINITY; }

    const float* ybase = ysrc + (size_t)b * N * 3;
    const int nchunks = N / YCHUNK;   // 2

    for (int c = 0; c < nchunks; ++c) {
        __syncthreads();  // previous compute phase done reading sy
        // Stage 4096 y-points (16 per thread), coalesced 3-dword loads.
#pragma unroll
        for (int j = 0; j < YCHUNK / THREADS; ++j) {
            const int    yj = j * THREADS + tid;
            const float* yp = ybase + (size_t)(c * YCHUNK + yj) * 3;
            float y0 = yp[0], y1 = yp[1], y2v = yp[2];
            float nn = fmaf(y0, y0, fmaf(y1, y1, y2v * y2v));
            sy[yj] = make_uint2(pk2(y0, y1), pk2(y2v, nn));
        }
        __syncthreads();

        // Barrier-free main loop, 8 MFMAs in flight per iteration.
#define LOADJ(j) uint2 lo##j = sy[(i + j) * 32 + col]
#define MFJ(j)                                                            \
        f32x16 ac##j = __builtin_amdgcn_mfma_f32_32x32x16_f16(            \
            __builtin_bit_cast(f16x8,                                     \
                make_uint4(lo##j.x, lo##j.y, 0u, 0u)), bf, zacc, 0, 0, 0)
        for (int i = 0; i < YCHUNK / 32; i += 8) {
            LOADJ(0); LOADJ(1); LOADJ(2); LOADJ(3);
            LOADJ(4); LOADJ(5); LOADJ(6); LOADJ(7);
            MFJ(0); MFJ(1); MFJ(2); MFJ(3);
            MFJ(4); MFJ(5); MFJ(6); MFJ(7);
#pragma unroll
            for (int r = 0; r < 16; ++r) {
                vmin[r] = fminf(fminf(vmin[r], ac0[r]), ac1[r]);  // v_min3
                vmin[r] = fminf(fminf(vmin[r], ac2[r]), ac3[r]);
                vmin[r] = fminf(fminf(vmin[r], ac4[r]), ac5[r]);
                vmin[r] = fminf(fminf(vmin[r], ac6[r]), ac7[r]);
            }
        }
#undef LOADJ
#undef MFJ
    }

    // Reduce 16 regs -> 1, then across the two row-halves (lane ^ 32).
    float v = vmin[0];
#pragma unroll
    for (int r = 1; r < 16; ++r) v = fminf(v, vmin[r]);
    v = fminf(v, __shfl_xor(v, 32));
    float d = v + fmaf(x0, x0, fmaf(x1, x1, x2 * x2));  // + |x|^2 in f32

    // Sum d over the 32 cols of this wave (both halves hold identical values).
#pragma unroll
    for (int off = 16; off > 0; off >>= 1) d += __shfl_xor(d, off);
    if (lane == 0) swave[wave] = d;
    __syncthreads();
    if (tid == 0) {
        float s = swave[0] + swave[1] + swave[2] + swave[3];
        int bid = blockIdx.x + gridDim.x * (blockIdx.y + gridDim.y * blockIdx.z);
        partials[bid] = s;
    }
}

// partials[0 .. nPerDir-1] = dir0 block sums, [nPerDir .. 2*nPerDir-1] = dir1.
__global__ __launch_bounds__(512) void finalize(
    const float* __restrict__ partials, const float* __restrict__ fbpp,
    float* __restrict__ out, int nPerDir, int totalPts)
{
    __shared__ float sw[8];
    const int tid = threadIdx.x;
    float v = (tid < 2 * nPerDir) ? partials[tid] : 0.0f;
#pragma unroll
    for (int off = 32; off > 0; off >>= 1) v += __shfl_xor(v, off);
    if ((tid & 63) == 0) sw[tid >> 6] = v;
    __syncthreads();
    if (tid == 0) {
        float s0 = sw[0] + sw[1] + sw[2] + sw[3];  // dir0 (waves 0-3)
        float s1 = sw[4] + sw[5] + sw[6] + sw[7];  // dir1 (waves 4-7)
        float inv = 1.0f / (float)totalPts;
        float dist = s0 * inv + s1 * inv;
        float rate = fbpp[0];
        out[0] = dist + rate;
        out[1] = dist;
        out[2] = rate;
    }
}

extern "C" void kernel_launch(void* const* d_in, const int* in_sizes, int n_in,
                              void* d_out, int out_size, void* d_ws, size_t ws_size,
                              hipStream_t stream) {
    const float* pred = (const float*)d_in[0];
    const float* targ = (const float*)d_in[1];
    const float* fbpp = (const float*)d_in[2];
    float* out = (float*)d_out;

    const int B = 4;
    const int N = in_sizes[0] / (B * 3);   // 8192
    float* partials = (float*)d_ws;        // 2 * B * (N/XPB) floats

    dim3 grid(N / XPB, B, 2);              // (64, 4, 2) = 512 blocks
    chamfer_kernel<<<grid, THREADS, 0, stream>>>(pred, targ, partials, N);

    const int nPerDir = (N / XPB) * B;     // 256
    finalize<<<1, 512, 0, stream>>>(partials, fbpp, out, nPerDir, B * N);
}